// Round 8
// baseline (584.688 us; speedup 1.0000x reference)
//
#include <hip/hip_runtime.h>

typedef unsigned short u16;
typedef unsigned int u32;
typedef __bf16 bf16x8 __attribute__((ext_vector_type(8)));
typedef float f32x4 __attribute__((ext_vector_type(4)));
typedef u32 u32x4 __attribute__((ext_vector_type(4)));
typedef u32 u32x2 __attribute__((ext_vector_type(2)));

union U8 { u32x4 u; u16 us[8]; bf16x8 bf; };

static __device__ __forceinline__ float b2f(u16 h) {
  union { u32 i; float f; } c; c.i = ((u32)h) << 16; return c.f;
}
static __device__ __forceinline__ u16 f2b(float f) {
  union { float f; u32 i; } c; c.f = f;
  u32 x = c.i;
  return (u16)((x + 0x7fffu + ((x >> 16) & 1u)) >> 16);
}
// pack 2 f32 -> 2 bf16 in one u32 (RTNE, identical to f2b pair)
static __device__ __forceinline__ u32 pk2(float a, float b) {
  u32 d;
  asm("v_cvt_pk_bf16_f32 %0, %1, %2" : "=v"(d) : "v"(a), "v"(b));
  return d;
}
// tanh-form GELU: v * sigmoid(2*0.79788456*(v + 0.044715 v^3)); |err vs erf-GELU| <= 3e-3
static __device__ __forceinline__ float gelu_f(float v) {
  float v2 = v * v;
  float ny2 = -2.0f * v * fmaf(0.0356774081f, v2, 0.7978845608f);   // -2y
  float sig = __builtin_amdgcn_rcpf(1.0f + __expf(ny2));
  return v * sig;
}

// async global->LDS DMA, 16B per lane, LDS dest = wave-uniform base + lane*16
#define G2LDS16(gp, lp)                                                                   \
  __builtin_amdgcn_global_load_lds((const __attribute__((address_space(1))) void*)(gp),   \
                                   (__attribute__((address_space(3))) void*)(lp), 16, 0, 0)

// ---------- weight transpose+convert: W[K][N] fp32 -> WT[N][K] bf16
__global__ __launch_bounds__(256) void wtrans(const float* __restrict__ W, u16* __restrict__ WT,
                                              int K, int N) {
  __shared__ float t[32][33];
  int n0 = blockIdx.x * 32, k0 = blockIdx.y * 32;
  int tx = threadIdx.x, ty = threadIdx.y;   // 32 x 8
#pragma unroll
  for (int r = 0; r < 4; ++r)
    t[ty + 8 * r][tx] = W[(long)(k0 + ty + 8 * r) * N + n0 + tx];
  __syncthreads();
#pragma unroll
  for (int r = 0; r < 4; ++r)
    WT[(long)(n0 + ty + 8 * r) * K + k0 + tx] = f2b(t[tx][ty + 8 * r]);
}

// ---------- LayerNorm: MODE 0 = shift+window gather (LN1), MODE 1 = direct rows (LN2)
// float2 loads (8B/lane coalesced) + packed u32 bf16 stores
template<int MODE>
__global__ __launch_bounds__(256) void ln_kernel(const float* __restrict__ src,
                                                 const float* __restrict__ g,
                                                 const float* __restrict__ b,
                                                 u16* __restrict__ dst) {
  int tok = blockIdx.x * 4 + (threadIdx.x >> 6);   // destination (windowed) token
  int lane = threadIdx.x & 63;
  long srow;
  if (MODE == 0) {
    int wg = tok / 49, i = tok % 49;
    int bimg = wg >> 4, wloc = wg & 15;
    int wh = wloc >> 2, ww = wloc & 3;
    int ih = i / 7, iw = i % 7;
    int hr = wh * 7 + ih + 3; if (hr >= 28) hr -= 28;  // roll(-3)
    int wr = ww * 7 + iw + 3; if (wr >= 28) wr -= 28;
    srow = (long)(bimg * 784 + hr * 28 + wr) * 384;
  } else {
    srow = (long)tok * 384;
  }
  const float* p = src + srow;
  float v[6];
#pragma unroll
  for (int t = 0; t < 3; ++t) {
    float2 z = *(const float2*)(p + (lane + 64 * t) * 2);
    v[2 * t] = z.x; v[2 * t + 1] = z.y;
  }
  float s = 0.f, ss = 0.f;
#pragma unroll
  for (int t = 0; t < 6; ++t) { s += v[t]; ss += v[t] * v[t]; }
  for (int m = 32; m; m >>= 1) { s += __shfl_xor(s, m); ss += __shfl_xor(ss, m); }
  float mean = s * (1.0f / 384.0f);
  float var  = ss * (1.0f / 384.0f) - mean * mean;
  float rs = rsqrtf(var + 1e-5f);
  u16* o = dst + (long)tok * 384;
#pragma unroll
  for (int t = 0; t < 3; ++t) {
    int ch = (lane + 64 * t) * 2;
    float2 gg = *(const float2*)(g + ch);
    float2 bb = *(const float2*)(b + ch);
    float r0 = (v[2 * t] - mean) * rs * gg.x + bb.x;
    float r1 = (v[2 * t + 1] - mean) * rs * gg.y + bb.y;
    *(u32*)&o[ch] = pk2(r0, r1);
  }
}

// ---------- big-tile GEMM: C[M][N] = A[M][K] @ BT[N][K]^T + bias
// BM=256 x BN=128 block, 4 waves, per-wave 128x64 output (acc[4][8]) — 2.67 MFMA per
// ds_read_b128 vs 2.0 at 64x64/wave, halved block count (less redundant B staging).
// m97-style single-buffer loop; both-sides XOR swizzle (verified, conflicts=0);
// m204 bijective XCD-chunked remap (grids not %8); swapped-operand D^T epilogues.
template<int EPI>
__global__ __launch_bounds__(256, 2) void gemm_big(
    const u16* __restrict__ A, const u16* __restrict__ BT,
    const float* __restrict__ bias, const float* __restrict__ xres,
    u16* __restrict__ Cb, float* __restrict__ Cf, int N, int K) {
  __shared__ __align__(16) u16 As[256 * 64];   // 32 KB
  __shared__ __align__(16) u16 Bs[128 * 64];   // 16 KB
  const int tid = threadIdx.x;
  const int wave = tid >> 6, lane = tid & 63, quad = lane >> 4, col = lane & 15;

  const int NY = (EPI == 0) ? 9 : (EPI == 1) ? 12 : 3;     // N / 128
  // bijective XCD-chunked remap (m204): works for any nwg
  const int nwg = gridDim.x * gridDim.y;
  const int orig = blockIdx.x + blockIdx.y * gridDim.x;
  const int q8 = nwg >> 3, r8 = nwg & 7;
  const int xcd = orig & 7, idx = orig >> 3;
  const int sid = (xcd < r8 ? xcd * (q8 + 1) : r8 * (q8 + 1) + (xcd - r8) * q8) + idx;
  const int mi = sid / NY, ni = sid - mi * NY;             // N-inner within the chunk
  const long m0 = (long)mi * 256;
  const int n0 = ni * 128;

  const int rm = (wave & 1) * 128, cn = (wave >> 1) * 64;
  f32x4 acc[4][8];                          // acc[j][i]: n-tile j, m-tile i
#pragma unroll
  for (int j = 0; j < 4; ++j)
#pragma unroll
    for (int i = 0; i < 8; ++i) acc[j][i] = f32x4{0.f, 0.f, 0.f, 0.f};

  const int K64 = K >> 6;
  const int sr = lane >> 3;                 // sub-row within 8-row stripe
  const int sc = (lane & 7) ^ sr;           // swizzled 16B-chunk index (involution)
  // A: wave stages rows [wave*64, wave*64+64) in 8 loads; B: rows [wave*32,+32) in 4
  const u16* gA = A  + (m0 + wave * 64 + sr) * (long)K + sc * 8;
  const u16* gB = BT + ((long)(n0 + wave * 32 + sr)) * K + sc * 8;

  for (int kt = 0; kt < K64; ++kt) {
    if (kt) __syncthreads();                // all waves done reading previous tile
#pragma unroll
    for (int c = 0; c < 8; ++c)
      G2LDS16(gA + (long)c * 8 * K + kt * 64, &As[wave * 4096 + c * 512]);
#pragma unroll
    for (int c = 0; c < 4; ++c)
      G2LDS16(gB + (long)c * 8 * K + kt * 64, &Bs[wave * 2048 + c * 512]);
    __syncthreads();                        // implicit vmcnt(0): tile ready
#pragma unroll
    for (int kk = 0; kk < 2; ++kk) {
      U8 af[8], bfr[4];
#pragma unroll
      for (int i = 0; i < 8; ++i) {
        int row = rm + i * 16 + col;
        int slot = (kk * 4 + quad) ^ (row & 7);
        af[i].u = *(const u32x4*)&As[row * 64 + slot * 8];
      }
#pragma unroll
      for (int j = 0; j < 4; ++j) {
        int row = cn + j * 16 + col;
        int slot = (kk * 4 + quad) ^ (row & 7);
        bfr[j].u = *(const u32x4*)&Bs[row * 64 + slot * 8];
      }
#pragma unroll
      for (int j = 0; j < 4; ++j)
#pragma unroll
        for (int i = 0; i < 8; ++i)
          acc[j][i] = __builtin_amdgcn_mfma_f32_16x16x32_bf16(bfr[j].bf, af[i].bf, acc[j][i], 0, 0, 0);
    }
  }

  // ---- epilogue (D^T layout: row = m0+rm+i*16+col, n = n0+cn+j*16+quad*4+r)
  if (EPI == 0 || EPI == 1) {
#pragma unroll
    for (int j = 0; j < 4; ++j) {
      int nb = n0 + cn + j * 16 + quad * 4;
      f32x4 bv = *(const f32x4*)&bias[nb];
#pragma unroll
      for (int i = 0; i < 8; ++i) {
        long row = m0 + rm + i * 16 + col;
        f32x4 v = acc[j][i] + bv;
        if (EPI == 1) {
#pragma unroll
          for (int r = 0; r < 4; ++r) v[r] = gelu_f(v[r]);
        }
        *(u32x2*)&Cb[row * N + nb] = u32x2{pk2(v[0], v[1]), pk2(v[2], v[3])};
      }
    }
  } else if (EPI == 2) {
#pragma unroll
    for (int i = 0; i < 8; ++i) {
      int row = (int)m0 + rm + i * 16 + col;
      int wg = row / 49, i49 = row - wg * 49;
      int bimg = wg >> 4, wloc = wg & 15;
      int wh = wloc >> 2, ww = wloc & 3;
      int ih = i49 / 7, iw = i49 - (i49 / 7) * 7;
      int ho = wh * 7 + ih + 3; if (ho >= 28) ho -= 28;   // roll(+3) back
      int wo = ww * 7 + iw + 3; if (wo >= 28) wo -= 28;
      long dstb = (long)(bimg * 784 + ho * 28 + wo) * 384;
#pragma unroll
      for (int j = 0; j < 4; ++j) {
        int nb = n0 + cn + j * 16 + quad * 4;
        f32x4 bv = *(const f32x4*)&bias[nb];
        f32x4 xr = *(const f32x4*)&xres[dstb + nb];
        f32x4 v = acc[j][i] + bv + xr;
        *(f32x4*)&Cf[dstb + nb] = v;
      }
    }
  } else {  // EPI == 3: fp32 RMW residual
#pragma unroll
    for (int i = 0; i < 8; ++i) {
      long rb = (long)((int)m0 + rm + i * 16 + col) * 384;
#pragma unroll
      for (int j = 0; j < 4; ++j) {
        int nb = n0 + cn + j * 16 + quad * 4;
        f32x4 bv = *(const f32x4*)&bias[nb];
        f32x4 old = *(const f32x4*)&Cf[rb + nb];
        f32x4 v = acc[j][i] + bv + old;
        *(f32x4*)&Cf[rb + nb] = v;
      }
    }
  }
}

// ---------- bias+mask table in SWAPPED C-fragment order:
// f32x4 at [((type*12+head)*16 + tj*4 + ti)*64 + quad*16 + c], elem r =
//   bias(i = ti*16+c, j = tj*16+quad*4+r); -1e30 padding for i>=49 or j>=49.
__global__ __launch_bounds__(256) void bmt_kernel(const float* __restrict__ rpb,
                                                  float* __restrict__ bmt) {
  int th = blockIdx.y;                       // type*12 + head
  int type = th / 12, head = th - type * 12;
  int e = blockIdx.x * 256 + threadIdx.x;    // [0,1024) per (type,head)
  int tj = e >> 8, ti = (e >> 6) & 3, quad = (e >> 4) & 3, c = e & 15;
  int i = ti * 16 + c;
  int ih = i / 7, iw = i - ih * 7;
  int regi = ((type & 2) ? ((ih < 4) ? 1 : 2) : 0) * 3 + ((type & 1) ? ((iw < 4) ? 1 : 2) : 0);
  f32x4 v;
#pragma unroll
  for (int r = 0; r < 4; ++r) {
    int j = tj * 16 + quad * 4 + r;
    float val = -1e30f;
    if (i < 49 && j < 49) {
      int jh = j / 7, jw = j - jh * 7;
      int idx = (ih - jh + 6) * 13 + (iw - jw + 6);
      val = rpb[idx * 12 + head];
      int regj = ((type & 2) ? ((jh < 4) ? 1 : 2) : 0) * 3 + ((type & 1) ? ((jw < 4) ? 1 : 2) : 0);
      if (regi != regj) val -= 100.0f;
    }
    v[r] = val;
  }
  ((f32x4*)bmt)[((long)th * 16 + tj * 4 + ti) * 64 + quad * 16 + c] = v;
}

// ---------- MFMA attention, swapped-QK^T design: wave = (window, head)
// S' = K·Q^T (A=K-frag, B=Q-frag), C-layout: lane holds S'[j=tj*16+quad*4+r][i=ti*16+c].
// Softmax over j: 16 in-lane + shfl_xor(16,32). P written row-major [i][j] to per-wave
// LDS with packed b64 (r's are consecutive j), read back as PV A-frags via plain
// contiguous ds_read_b128. V B-frags: 32 scalar reads from stride-130 Vs (conflict-free).
__global__ __launch_bounds__(256) void attn_kernel(const u16* __restrict__ qkv,
                                                   const float* __restrict__ bmt,
                                                   u16* __restrict__ obuf) {
  __shared__ __align__(16) u16 Ks[64 * 136];     // K row-major [j][d'], stride 136
  __shared__ __align__(16) u16 Vs[64 * 130];     // V row-major [j][d'], stride 130
  __shared__ __align__(16) u16 PL[4 * 64 * 72];  // per-wave P [i][j], stride 72
  const int w = blockIdx.x, h0 = blockIdx.y * 4;
  const int tid = threadIdx.x;
  const int hl = tid >> 6, lane = tid & 63, quad = lane >> 4, c = lane & 15;
  const int head = h0 + hl;
  const int wloc = w & 15;
  const int type = (((wloc >> 2) == 3) ? 2 : 0) + (((wloc & 3) == 3) ? 1 : 0);

  // stage K (u32x4 chunks, 128 u16 per row); zero rows j>=49 (mask padding must be finite)
#pragma unroll
  for (int it = 0; it < 4; ++it) {
    int cc = tid + it * 256;                 // 64 rows x 16 chunks
    int j = cc >> 4, ch = cc & 15;
    u32x4 val = {0u, 0u, 0u, 0u};
    if (j < 49)
      val = *(const u32x4*)(qkv + ((long)w * 49 + j) * 1152 + 384 + h0 * 32 + ch * 8);
    *(u32x4*)&Ks[j * 136 + ch * 8] = val;
  }
  // stage V: 64 rows x 64 u32-chunks = 128 u16 per row; zero rows j>=49
#pragma unroll
  for (int it = 0; it < 16; ++it) {
    int cc = tid + it * 256;
    int j = cc >> 6, c4 = cc & 63;
    u32 val = 0u;
    if (j < 49)
      val = *(const u32*)(qkv + ((long)w * 49 + j) * 1152 + 768 + h0 * 32 + c4 * 2);
    *(u32*)&Vs[j * 130 + c4 * 2] = val;
  }

  // Q B-frags from global: lane holds Q[i=ti*16+c][d=quad*8+e]  (= B[k=d][n=i])
  U8 qf[4];
#pragma unroll
  for (int ti = 0; ti < 4; ++ti)
    qf[ti].u = *(const u32x4*)(qkv + ((long)w * 49 + ti * 16 + c) * 1152 + head * 32 + quad * 8);
  __syncthreads();

  // K A-frags: lane holds K[j=tj*16+c][d=quad*8+e]; S' = K·Q^T (one MFMA per tile, K=32)
  U8 kf[4];
#pragma unroll
  for (int tj = 0; tj < 4; ++tj)
    kf[tj].u = *(const u32x4*)&Ks[(tj * 16 + c) * 136 + hl * 32 + quad * 8];
  f32x4 s[4][4];                             // [tj][ti]: S'[j][i]
#pragma unroll
  for (int tj = 0; tj < 4; ++tj)
#pragma unroll
    for (int ti = 0; ti < 4; ++ti)
      s[tj][ti] = __builtin_amdgcn_mfma_f32_16x16x32_bf16(kf[tj].bf, qf[ti].bf,
                                                          f32x4{0.f, 0.f, 0.f, 0.f}, 0, 0, 0);

  // scale + bias/mask (table in matching fragment order -> coalesced f32x4)
  const f32x4* btb = (const f32x4*)bmt + ((long)(type * 12 + head) * 16) * 64 + quad * 16 + c;
#pragma unroll
  for (int tj = 0; tj < 4; ++tj)
#pragma unroll
    for (int ti = 0; ti < 4; ++ti) {
      f32x4 bv = btb[(tj * 4 + ti) * 64];
#pragma unroll
      for (int r = 0; r < 4; ++r)
        s[tj][ti][r] = fmaf(s[tj][ti][r], 0.17677669529663689f, bv[r]);
    }

  // softmax over j for each i (= per ti, fixed c): 16 in-lane values + quads via xor 16,32
#pragma unroll
  for (int ti = 0; ti < 4; ++ti) {
    float m = -1e30f;
#pragma unroll
    for (int tj = 0; tj < 4; ++tj)
#pragma unroll
      for (int r = 0; r < 4; ++r) m = fmaxf(m, s[tj][ti][r]);
    m = fmaxf(m, __shfl_xor(m, 16));
    m = fmaxf(m, __shfl_xor(m, 32));
    float l = 0.f;
#pragma unroll
    for (int tj = 0; tj < 4; ++tj)
#pragma unroll
      for (int r = 0; r < 4; ++r) {
        float p = __expf(s[tj][ti][r] - m);
        s[tj][ti][r] = p;
        l += p;
      }
    l += __shfl_xor(l, 16);
    l += __shfl_xor(l, 32);
    float inv = 1.0f / l;
#pragma unroll
    for (int tj = 0; tj < 4; ++tj)
#pragma unroll
      for (int r = 0; r < 4; ++r) s[tj][ti][r] *= inv;
  }

  // write P row-major [i][j] (bf16): r=0..3 are consecutive j -> one b64 per (ti,tj)
#pragma unroll
  for (int ti = 0; ti < 4; ++ti)
#pragma unroll
    for (int tj = 0; tj < 4; ++tj) {
      u32 lo = pk2(s[tj][ti][0], s[tj][ti][1]);
      u32 hi = pk2(s[tj][ti][2], s[tj][ti][3]);
      *(u32x2*)&PL[hl * 4608 + (ti * 16 + c) * 72 + tj * 16 + quad * 4] = u32x2{lo, hi};
    }

  // PV: O[i][d] = sum_j P[i][j] V[j][d]
  f32x4 oacc[4][2];
#pragma unroll
  for (int t2 = 0; t2 < 4; ++t2) {
    oacc[t2][0] = f32x4{0.f, 0.f, 0.f, 0.f};
    oacc[t2][1] = f32x4{0.f, 0.f, 0.f, 0.f};
  }
#pragma unroll
  for (int kk = 0; kk < 2; ++kk) {
    U8 pa[4];                                // A-frag: P[i=t2*16+c][j=kk*32+quad*8+e]
#pragma unroll
    for (int t2 = 0; t2 < 4; ++t2)
      pa[t2].u = *(const u32x4*)&PL[hl * 4608 + (t2 * 16 + c) * 72 + kk * 32 + quad * 8];
    U8 vf[2];                                // B-frag: V[j=kk*32+quad*8+e][d=td*16+c]
#pragma unroll
    for (int td = 0; td < 2; ++td)
#pragma unroll
      for (int e = 0; e < 8; ++e)
        vf[td].us[e] = Vs[(kk * 32 + quad * 8 + e) * 130 + hl * 32 + td * 16 + c];
#pragma unroll
    for (int t2 = 0; t2 < 4; ++t2)
#pragma unroll
      for (int td = 0; td < 2; ++td)
        oacc[t2][td] = __builtin_amdgcn_mfma_f32_16x16x32_bf16(pa[t2].bf, vf[td].bf, oacc[t2][td], 0, 0, 0);
  }

  // store O rows i<49; lane holds O[i=t2*16+quad*4+r][d=td*16+c]
#pragma unroll
  for (int t2 = 0; t2 < 4; ++t2)
#pragma unroll
    for (int r = 0; r < 4; ++r) {
      int i = t2 * 16 + quad * 4 + r;
      if (i < 49) {
        u16* op = obuf + ((long)w * 49 + i) * 384 + head * 32 + c;
        op[0]  = f2b(oacc[t2][0][r]);
        op[16] = f2b(oacc[t2][1][r]);
      }
    }
}

extern "C" void kernel_launch(void* const* d_in, const int* in_sizes, int n_in,
                              void* d_out, int out_size, void* d_ws, size_t ws_size,
                              hipStream_t stream) {
  const float* x     = (const float*)d_in[0];
  const float* n1g   = (const float*)d_in[1];
  const float* n1b   = (const float*)d_in[2];
  const float* qkvw  = (const float*)d_in[3];
  const float* qkvb  = (const float*)d_in[4];
  const float* projw = (const float*)d_in[5];
  const float* projb = (const float*)d_in[6];
  const float* rpb   = (const float*)d_in[7];
  const float* n2g   = (const float*)d_in[8];
  const float* n2b   = (const float*)d_in[9];
  const float* fc1w  = (const float*)d_in[10];
  const float* fc1b  = (const float*)d_in[11];
  const float* fc2w  = (const float*)d_in[12];
  const float* fc2b  = (const float*)d_in[13];
  float* out = (float*)d_out;

  // ws layout (u16 units): weights 1.77M | region A 19.27M (xw -> obuf -> abuf) | region B 77.07M (qkv -> mid)
  u16* qkvwT  = (u16*)d_ws;                 // 442368
  u16* projwT = qkvwT + 442368;             // 147456
  u16* fc1wT  = projwT + 147456;            // 589824
  u16* fc2wT  = fc1wT + 589824;             // 589824  (ends 1769472)
  u16* wsA    = fc2wT + 589824;             // 19267584 (ends 21037056)
  u16* wsB    = wsA + 19267584;             // 77070336 (ends 98107392 = 196.2 MB)
  u16* xw   = wsA;        // LN1 out [50176][384]
  u16* obuf = wsA;        // attention out (xw dead after qkv GEMM)
  u16* abuf = wsA;        // LN2 out (obuf dead after proj)
  u16* qkvB = wsB;        // [50176][1152]
  u16* midB = wsB;        // [50176][1536] (qkv dead after attention)
  float* bmtb = (float*)qkvwT;  // 786KB bias+mask table aliases qkvwT (dead after qkv GEMM)

  // weights -> bf16 W^T
  wtrans<<<dim3(36, 12), dim3(32, 8), 0, stream>>>(qkvw, qkvwT, 384, 1152);
  wtrans<<<dim3(12, 12), dim3(32, 8), 0, stream>>>(projw, projwT, 384, 384);
  wtrans<<<dim3(48, 12), dim3(32, 8), 0, stream>>>(fc1w, fc1wT, 384, 1536);
  wtrans<<<dim3(12, 48), dim3(32, 8), 0, stream>>>(fc2w, fc2wT, 1536, 384);

  // 1. LN1 + shift + window -> xw
  ln_kernel<0><<<12544, 256, 0, stream>>>(x, n1g, n1b, xw);
  // 2. QKV GEMM -> qkvB
  gemm_big<0><<<dim3(196, 9), 256, 0, stream>>>(xw, qkvwT, qkvb, nullptr, qkvB, nullptr, 1152, 384);
  // 2b. bias+mask table (qkvwT now dead)
  bmt_kernel<<<dim3(4, 48), 256, 0, stream>>>(rpb, bmtb);
  // 3. windowed attention (MFMA, swapped QK^T) -> obuf
  attn_kernel<<<dim3(1024, 3), 256, 0, stream>>>(qkvB, bmtb, obuf);
  // 4. proj GEMM + reverse-shift scatter + shortcut -> d_out (x2, fp32)
  gemm_big<2><<<dim3(196, 3), 256, 0, stream>>>(obuf, projwT, projb, x, nullptr, out, 384, 384);
  // 5. LN2 -> abuf
  ln_kernel<1><<<12544, 256, 0, stream>>>(out, n2g, n2b, abuf);
  // 6. FC1 + GELU -> midB
  gemm_big<1><<<dim3(196, 12), 256, 0, stream>>>(abuf, fc1wT, fc1b, nullptr, midB, nullptr, 1536, 384);
  // 7. FC2 + residual RMW -> d_out
  gemm_big<3><<<dim3(196, 3), 256, 0, stream>>>(midB, fc2wT, fc2b, nullptr, nullptr, out, 384, 1536);
}

// Round 9
// 563.270 us; speedup vs baseline: 1.0380x; 1.0380x over previous
//
#include <hip/hip_runtime.h>

typedef unsigned short u16;
typedef unsigned int u32;
typedef __bf16 bf16x8 __attribute__((ext_vector_type(8)));
typedef float f32x4 __attribute__((ext_vector_type(4)));
typedef u32 u32x4 __attribute__((ext_vector_type(4)));
typedef u32 u32x2 __attribute__((ext_vector_type(2)));

union U8 { u32x4 u; u16 us[8]; bf16x8 bf; };

static __device__ __forceinline__ float b2f(u16 h) {
  union { u32 i; float f; } c; c.i = ((u32)h) << 16; return c.f;
}
static __device__ __forceinline__ u16 f2b(float f) {
  union { float f; u32 i; } c; c.f = f;
  u32 x = c.i;
  return (u16)((x + 0x7fffu + ((x >> 16) & 1u)) >> 16);
}
// pack 2 f32 -> 2 bf16 in one u32 (RTNE, identical to f2b pair)
static __device__ __forceinline__ u32 pk2(float a, float b) {
  u32 d;
  asm("v_cvt_pk_bf16_f32 %0, %1, %2" : "=v"(d) : "v"(a), "v"(b));
  return d;
}
// tanh-form GELU: v * sigmoid(2*0.79788456*(v + 0.044715 v^3)); |err vs erf-GELU| <= 3e-3
static __device__ __forceinline__ float gelu_f(float v) {
  float v2 = v * v;
  float ny2 = -2.0f * v * fmaf(0.0356774081f, v2, 0.7978845608f);   // -2y
  float sig = __builtin_amdgcn_rcpf(1.0f + __expf(ny2));
  return v * sig;
}

// async global->LDS DMA, 16B per lane, LDS dest = wave-uniform base + lane*16
#define G2LDS16(gp, lp)                                                                   \
  __builtin_amdgcn_global_load_lds((const __attribute__((address_space(1))) void*)(gp),   \
                                   (__attribute__((address_space(3))) void*)(lp), 16, 0, 0)

// ---------- weight transpose+convert: W[K][N] fp32 -> WT[N][K] bf16
__global__ __launch_bounds__(256) void wtrans(const float* __restrict__ W, u16* __restrict__ WT,
                                              int K, int N) {
  __shared__ float t[32][33];
  int n0 = blockIdx.x * 32, k0 = blockIdx.y * 32;
  int tx = threadIdx.x, ty = threadIdx.y;   // 32 x 8
#pragma unroll
  for (int r = 0; r < 4; ++r)
    t[ty + 8 * r][tx] = W[(long)(k0 + ty + 8 * r) * N + n0 + tx];
  __syncthreads();
#pragma unroll
  for (int r = 0; r < 4; ++r)
    WT[(long)(n0 + ty + 8 * r) * K + k0 + tx] = f2b(t[tx][ty + 8 * r]);
}

// ---------- LayerNorm: MODE 0 = shift+window gather (LN1), MODE 1 = direct rows (LN2)
// float2 loads (8B/lane coalesced) + packed u32 bf16 stores
template<int MODE>
__global__ __launch_bounds__(256) void ln_kernel(const float* __restrict__ src,
                                                 const float* __restrict__ g,
                                                 const float* __restrict__ b,
                                                 u16* __restrict__ dst) {
  int tok = blockIdx.x * 4 + (threadIdx.x >> 6);   // destination (windowed) token
  int lane = threadIdx.x & 63;
  long srow;
  if (MODE == 0) {
    int wg = tok / 49, i = tok % 49;
    int bimg = wg >> 4, wloc = wg & 15;
    int wh = wloc >> 2, ww = wloc & 3;
    int ih = i / 7, iw = i % 7;
    int hr = wh * 7 + ih + 3; if (hr >= 28) hr -= 28;  // roll(-3)
    int wr = ww * 7 + iw + 3; if (wr >= 28) wr -= 28;
    srow = (long)(bimg * 784 + hr * 28 + wr) * 384;
  } else {
    srow = (long)tok * 384;
  }
  const float* p = src + srow;
  float v[6];
#pragma unroll
  for (int t = 0; t < 3; ++t) {
    float2 z = *(const float2*)(p + (lane + 64 * t) * 2);
    v[2 * t] = z.x; v[2 * t + 1] = z.y;
  }
  float s = 0.f, ss = 0.f;
#pragma unroll
  for (int t = 0; t < 6; ++t) { s += v[t]; ss += v[t] * v[t]; }
  for (int m = 32; m; m >>= 1) { s += __shfl_xor(s, m); ss += __shfl_xor(ss, m); }
  float mean = s * (1.0f / 384.0f);
  float var  = ss * (1.0f / 384.0f) - mean * mean;
  float rs = rsqrtf(var + 1e-5f);
  u16* o = dst + (long)tok * 384;
#pragma unroll
  for (int t = 0; t < 3; ++t) {
    int ch = (lane + 64 * t) * 2;
    float2 gg = *(const float2*)(g + ch);
    float2 bb = *(const float2*)(b + ch);
    float r0 = (v[2 * t] - mean) * rs * gg.x + bb.x;
    float r1 = (v[2 * t + 1] - mean) * rs * gg.y + bb.y;
    *(u32*)&o[ch] = pk2(r0, r1);
  }
}

// ---------- big-tile GEMM: C[M][N] = A[M][K] @ BT[N][K]^T + bias
// Round-7 verified 128x128 geometry (4 waves, 64x64/wave, both-sides XOR swizzle,
// D^T epilogues) + T4 counted-vmcnt double-buffer pipeline:
//   prologue stages tiles 0,1; each step waits vmcnt(8) (own 8 oldest = current tile,
//   next tile's 8 stay IN FLIGHT across both raw s_barriers), computes, then restages.
// WAR safe: STAGE(buf) issued only after the barrier following all waves' ds_reads of
// buf; vmcnt retires in issue order (m135); branches wave-uniform (no barrier divergence).
template<int EPI>
__global__ __launch_bounds__(256, 2) void gemm_big(
    const u16* __restrict__ A, const u16* __restrict__ BT,
    const float* __restrict__ bias, const float* __restrict__ xres,
    u16* __restrict__ Cb, float* __restrict__ Cf, int N, int K) {
  __shared__ __align__(16) u16 As0[128 * 64];
  __shared__ __align__(16) u16 Bs0[128 * 64];
  __shared__ __align__(16) u16 As1[128 * 64];
  __shared__ __align__(16) u16 Bs1[128 * 64];
  const int tid = threadIdx.x;
  const int wave = tid >> 6, lane = tid & 63, quad = lane >> 4, col = lane & 15;

  const int NY = (EPI == 0) ? 9 : (EPI == 1) ? 12 : 3;     // N / 128
  // bijective XCD-chunked remap (m204): works for any nwg
  const int nwg = gridDim.x * gridDim.y;
  const int orig = blockIdx.x + blockIdx.y * gridDim.x;
  const int q8 = nwg >> 3, r8 = nwg & 7;
  const int xcd = orig & 7, idx = orig >> 3;
  const int sid = (xcd < r8 ? xcd * (q8 + 1) : r8 * (q8 + 1) + (xcd - r8) * q8) + idx;
  const int mi = sid / NY, ni = sid - mi * NY;             // N-inner within the chunk
  const long m0 = (long)mi * 128;
  const int n0 = ni * 128;

  const int rm = (wave & 1) * 64, cn = (wave >> 1) * 64;
  f32x4 acc[4][4];                          // acc[j][i]: n-tile j, m-tile i
#pragma unroll
  for (int j = 0; j < 4; ++j)
#pragma unroll
    for (int i = 0; i < 4; ++i) acc[j][i] = f32x4{0.f, 0.f, 0.f, 0.f};

  const int K64 = K >> 6;                   // 6 or 24 — always even
  const int sr = lane >> 3;                 // sub-row within 8-row stripe
  const int sc = (lane & 7) ^ sr;           // swizzled 16B-chunk index (involution)
  const u16* gA = A  + (m0 + wave * 32 + sr) * (long)K + sc * 8;
  const u16* gB = BT + ((long)(n0 + wave * 32 + sr)) * K + sc * 8;

#define STAGE(kt, AS, BS)                                                        \
  {                                                                              \
    _Pragma("unroll")                                                            \
    for (int c = 0; c < 4; ++c) {                                                \
      G2LDS16(gA + (long)c * 8 * K + (kt) * 64, &AS[wave * 2048 + c * 512]);     \
      G2LDS16(gB + (long)c * 8 * K + (kt) * 64, &BS[wave * 2048 + c * 512]);     \
    }                                                                            \
  }

#define COMPUTE(AS, BS)                                                          \
  {                                                                              \
    _Pragma("unroll")                                                            \
    for (int kk = 0; kk < 2; ++kk) {                                             \
      U8 af[4], bfr[4];                                                          \
      _Pragma("unroll")                                                          \
      for (int i = 0; i < 4; ++i) {                                              \
        int row = rm + i * 16 + col;                                             \
        int slot = (kk * 4 + quad) ^ (row & 7);                                  \
        af[i].u = *(const u32x4*)&AS[row * 64 + slot * 8];                       \
      }                                                                          \
      _Pragma("unroll")                                                          \
      for (int j = 0; j < 4; ++j) {                                              \
        int row = cn + j * 16 + col;                                             \
        int slot = (kk * 4 + quad) ^ (row & 7);                                  \
        bfr[j].u = *(const u32x4*)&BS[row * 64 + slot * 8];                      \
      }                                                                          \
      _Pragma("unroll")                                                          \
      for (int j = 0; j < 4; ++j)                                                \
        _Pragma("unroll")                                                        \
        for (int i = 0; i < 4; ++i)                                              \
          acc[j][i] = __builtin_amdgcn_mfma_f32_16x16x32_bf16(bfr[j].bf, af[i].bf, acc[j][i], 0, 0, 0); \
    }                                                                            \
  }

  STAGE(0, As0, Bs0);                       // 8 loads in flight
  STAGE(1, As1, Bs1);                       // 16 in flight
  for (int kt = 0; kt + 2 <= K64; kt += 2) {
    // ---- tile kt in buf0: wait own oldest 8 (tile kt); tile kt+1's 8 stay in flight
    asm volatile("s_waitcnt vmcnt(8)" ::: "memory");
    __builtin_amdgcn_s_barrier();
    __builtin_amdgcn_sched_barrier(0);
    COMPUTE(As0, Bs0);
    __builtin_amdgcn_sched_barrier(0);
    __builtin_amdgcn_s_barrier();           // all waves done reading buf0
    __builtin_amdgcn_sched_barrier(0);
    if (kt + 2 < K64) {
      STAGE(kt + 2, As0, Bs0);
      asm volatile("s_waitcnt vmcnt(8)" ::: "memory");   // tile kt+1 landed
    } else {
      asm volatile("s_waitcnt vmcnt(0)" ::: "memory");   // last pair: drain
    }
    // ---- tile kt+1 in buf1
    __builtin_amdgcn_s_barrier();
    __builtin_amdgcn_sched_barrier(0);
    COMPUTE(As1, Bs1);
    __builtin_amdgcn_sched_barrier(0);
    __builtin_amdgcn_s_barrier();           // all waves done reading buf1
    __builtin_amdgcn_sched_barrier(0);
    if (kt + 3 < K64) STAGE(kt + 3, As1, Bs1);
  }
#undef STAGE
#undef COMPUTE

  // ---- epilogue (D^T layout: row = m0+rm+i*16+col, n = n0+cn+j*16+quad*4+r)
  if (EPI == 0 || EPI == 1) {
#pragma unroll
    for (int j = 0; j < 4; ++j) {
      int nb = n0 + cn + j * 16 + quad * 4;
      f32x4 bv = *(const f32x4*)&bias[nb];
#pragma unroll
      for (int i = 0; i < 4; ++i) {
        long row = m0 + rm + i * 16 + col;
        f32x4 v = acc[j][i] + bv;
        if (EPI == 1) {
#pragma unroll
          for (int r = 0; r < 4; ++r) v[r] = gelu_f(v[r]);
        }
        *(u32x2*)&Cb[row * N + nb] = u32x2{pk2(v[0], v[1]), pk2(v[2], v[3])};
      }
    }
  } else if (EPI == 2) {
#pragma unroll
    for (int i = 0; i < 4; ++i) {
      int row = (int)m0 + rm + i * 16 + col;
      int wg = row / 49, i49 = row - wg * 49;
      int bimg = wg >> 4, wloc = wg & 15;
      int wh = wloc >> 2, ww = wloc & 3;
      int ih = i49 / 7, iw = i49 - (i49 / 7) * 7;
      int ho = wh * 7 + ih + 3; if (ho >= 28) ho -= 28;   // roll(+3) back
      int wo = ww * 7 + iw + 3; if (wo >= 28) wo -= 28;
      long dstb = (long)(bimg * 784 + ho * 28 + wo) * 384;
#pragma unroll
      for (int j = 0; j < 4; ++j) {
        int nb = n0 + cn + j * 16 + quad * 4;
        f32x4 bv = *(const f32x4*)&bias[nb];
        f32x4 xr = *(const f32x4*)&xres[dstb + nb];
        f32x4 v = acc[j][i] + bv + xr;
        *(f32x4*)&Cf[dstb + nb] = v;
      }
    }
  } else {  // EPI == 3: fp32 RMW residual
#pragma unroll
    for (int i = 0; i < 4; ++i) {
      long rb = (long)((int)m0 + rm + i * 16 + col) * 384;
#pragma unroll
      for (int j = 0; j < 4; ++j) {
        int nb = n0 + cn + j * 16 + quad * 4;
        f32x4 bv = *(const f32x4*)&bias[nb];
        f32x4 old = *(const f32x4*)&Cf[rb + nb];
        f32x4 v = acc[j][i] + bv + old;
        *(f32x4*)&Cf[rb + nb] = v;
      }
    }
  }
}

// ---------- bias+mask table in SWAPPED C-fragment order:
// f32x4 at [((type*12+head)*16 + tj*4 + ti)*64 + quad*16 + c], elem r =
//   bias(i = ti*16+c, j = tj*16+quad*4+r); -1e30 padding for i>=49 or j>=49.
__global__ __launch_bounds__(256) void bmt_kernel(const float* __restrict__ rpb,
                                                  float* __restrict__ bmt) {
  int th = blockIdx.y;                       // type*12 + head
  int type = th / 12, head = th - type * 12;
  int e = blockIdx.x * 256 + threadIdx.x;    // [0,1024) per (type,head)
  int tj = e >> 8, ti = (e >> 6) & 3, quad = (e >> 4) & 3, c = e & 15;
  int i = ti * 16 + c;
  int ih = i / 7, iw = i - ih * 7;
  int regi = ((type & 2) ? ((ih < 4) ? 1 : 2) : 0) * 3 + ((type & 1) ? ((iw < 4) ? 1 : 2) : 0);
  f32x4 v;
#pragma unroll
  for (int r = 0; r < 4; ++r) {
    int j = tj * 16 + quad * 4 + r;
    float val = -1e30f;
    if (i < 49 && j < 49) {
      int jh = j / 7, jw = j - jh * 7;
      int idx = (ih - jh + 6) * 13 + (iw - jw + 6);
      val = rpb[idx * 12 + head];
      int regj = ((type & 2) ? ((jh < 4) ? 1 : 2) : 0) * 3 + ((type & 1) ? ((jw < 4) ? 1 : 2) : 0);
      if (regi != regj) val -= 100.0f;
    }
    v[r] = val;
  }
  ((f32x4*)bmt)[((long)th * 16 + tj * 4 + ti) * 64 + quad * 16 + c] = v;
}

// ---------- MFMA attention, swapped-QK^T design: wave = (window, head)
// S' = K·Q^T (A=K-frag, B=Q-frag), C-layout: lane holds S'[j=tj*16+quad*4+r][i=ti*16+c].
// Softmax over j: 16 in-lane + shfl_xor(16,32). P written row-major [i][j] to per-wave
// LDS with packed b64 (r's are consecutive j), read back as PV A-frags via plain
// contiguous ds_read_b128. V B-frags: 32 scalar reads from stride-130 Vs (conflict-free).
__global__ __launch_bounds__(256) void attn_kernel(const u16* __restrict__ qkv,
                                                   const float* __restrict__ bmt,
                                                   u16* __restrict__ obuf) {
  __shared__ __align__(16) u16 Ks[64 * 136];     // K row-major [j][d'], stride 136
  __shared__ __align__(16) u16 Vs[64 * 130];     // V row-major [j][d'], stride 130
  __shared__ __align__(16) u16 PL[4 * 64 * 72];  // per-wave P [i][j], stride 72
  const int w = blockIdx.x, h0 = blockIdx.y * 4;
  const int tid = threadIdx.x;
  const int hl = tid >> 6, lane = tid & 63, quad = lane >> 4, c = lane & 15;
  const int head = h0 + hl;
  const int wloc = w & 15;
  const int type = (((wloc >> 2) == 3) ? 2 : 0) + (((wloc & 3) == 3) ? 1 : 0);

  // stage K (u32x4 chunks, 128 u16 per row); zero rows j>=49 (mask padding must be finite)
#pragma unroll
  for (int it = 0; it < 4; ++it) {
    int cc = tid + it * 256;                 // 64 rows x 16 chunks
    int j = cc >> 4, ch = cc & 15;
    u32x4 val = {0u, 0u, 0u, 0u};
    if (j < 49)
      val = *(const u32x4*)(qkv + ((long)w * 49 + j) * 1152 + 384 + h0 * 32 + ch * 8);
    *(u32x4*)&Ks[j * 136 + ch * 8] = val;
  }
  // stage V: 64 rows x 64 u32-chunks = 128 u16 per row; zero rows j>=49
#pragma unroll
  for (int it = 0; it < 16; ++it) {
    int cc = tid + it * 256;
    int j = cc >> 6, c4 = cc & 63;
    u32 val = 0u;
    if (j < 49)
      val = *(const u32*)(qkv + ((long)w * 49 + j) * 1152 + 768 + h0 * 32 + c4 * 2);
    *(u32*)&Vs[j * 130 + c4 * 2] = val;
  }

  // Q B-frags from global: lane holds Q[i=ti*16+c][d=quad*8+e]  (= B[k=d][n=i])
  U8 qf[4];
#pragma unroll
  for (int ti = 0; ti < 4; ++ti)
    qf[ti].u = *(const u32x4*)(qkv + ((long)w * 49 + ti * 16 + c) * 1152 + head * 32 + quad * 8);
  __syncthreads();

  // K A-frags: lane holds K[j=tj*16+c][d=quad*8+e]; S' = K·Q^T (one MFMA per tile, K=32)
  U8 kf[4];
#pragma unroll
  for (int tj = 0; tj < 4; ++tj)
    kf[tj].u = *(const u32x4*)&Ks[(tj * 16 + c) * 136 + hl * 32 + quad * 8];
  f32x4 s[4][4];                             // [tj][ti]: S'[j][i]
#pragma unroll
  for (int tj = 0; tj < 4; ++tj)
#pragma unroll
    for (int ti = 0; ti < 4; ++ti)
      s[tj][ti] = __builtin_amdgcn_mfma_f32_16x16x32_bf16(kf[tj].bf, qf[ti].bf,
                                                          f32x4{0.f, 0.f, 0.f, 0.f}, 0, 0, 0);

  // scale + bias/mask (table in matching fragment order -> coalesced f32x4)
  const f32x4* btb = (const f32x4*)bmt + ((long)(type * 12 + head) * 16) * 64 + quad * 16 + c;
#pragma unroll
  for (int tj = 0; tj < 4; ++tj)
#pragma unroll
    for (int ti = 0; ti < 4; ++ti) {
      f32x4 bv = btb[(tj * 4 + ti) * 64];
#pragma unroll
      for (int r = 0; r < 4; ++r)
        s[tj][ti][r] = fmaf(s[tj][ti][r], 0.17677669529663689f, bv[r]);
    }

  // softmax over j for each i (= per ti, fixed c): 16 in-lane values + quads via xor 16,32
#pragma unroll
  for (int ti = 0; ti < 4; ++ti) {
    float m = -1e30f;
#pragma unroll
    for (int tj = 0; tj < 4; ++tj)
#pragma unroll
      for (int r = 0; r < 4; ++r) m = fmaxf(m, s[tj][ti][r]);
    m = fmaxf(m, __shfl_xor(m, 16));
    m = fmaxf(m, __shfl_xor(m, 32));
    float l = 0.f;
#pragma unroll
    for (int tj = 0; tj < 4; ++tj)
#pragma unroll
      for (int r = 0; r < 4; ++r) {
        float p = __expf(s[tj][ti][r] - m);
        s[tj][ti][r] = p;
        l += p;
      }
    l += __shfl_xor(l, 16);
    l += __shfl_xor(l, 32);
    float inv = 1.0f / l;
#pragma unroll
    for (int tj = 0; tj < 4; ++tj)
#pragma unroll
      for (int r = 0; r < 4; ++r) s[tj][ti][r] *= inv;
  }

  // write P row-major [i][j] (bf16): r=0..3 are consecutive j -> one b64 per (ti,tj)
#pragma unroll
  for (int ti = 0; ti < 4; ++ti)
#pragma unroll
    for (int tj = 0; tj < 4; ++tj) {
      u32 lo = pk2(s[tj][ti][0], s[tj][ti][1]);
      u32 hi = pk2(s[tj][ti][2], s[tj][ti][3]);
      *(u32x2*)&PL[hl * 4608 + (ti * 16 + c) * 72 + tj * 16 + quad * 4] = u32x2{lo, hi};
    }

  // PV: O[i][d] = sum_j P[i][j] V[j][d]
  f32x4 oacc[4][2];
#pragma unroll
  for (int t2 = 0; t2 < 4; ++t2) {
    oacc[t2][0] = f32x4{0.f, 0.f, 0.f, 0.f};
    oacc[t2][1] = f32x4{0.f, 0.f, 0.f, 0.f};
  }
#pragma unroll
  for (int kk = 0; kk < 2; ++kk) {
    U8 pa[4];                                // A-frag: P[i=t2*16+c][j=kk*32+quad*8+e]
#pragma unroll
    for (int t2 = 0; t2 < 4; ++t2)
      pa[t2].u = *(const u32x4*)&PL[hl * 4608 + (t2 * 16 + c) * 72 + kk * 32 + quad * 8];
    U8 vf[2];                                // B-frag: V[j=kk*32+quad*8+e][d=td*16+c]
#pragma unroll
    for (int td = 0; td < 2; ++td)
#pragma unroll
      for (int e = 0; e < 8; ++e)
        vf[td].us[e] = Vs[(kk * 32 + quad * 8 + e) * 130 + hl * 32 + td * 16 + c];
#pragma unroll
    for (int t2 = 0; t2 < 4; ++t2)
#pragma unroll
      for (int td = 0; td < 2; ++td)
        oacc[t2][td] = __builtin_amdgcn_mfma_f32_16x16x32_bf16(pa[t2].bf, vf[td].bf, oacc[t2][td], 0, 0, 0);
  }

  // store O rows i<49; lane holds O[i=t2*16+quad*4+r][d=td*16+c]
#pragma unroll
  for (int t2 = 0; t2 < 4; ++t2)
#pragma unroll
    for (int r = 0; r < 4; ++r) {
      int i = t2 * 16 + quad * 4 + r;
      if (i < 49) {
        u16* op = obuf + ((long)w * 49 + i) * 384 + head * 32 + c;
        op[0]  = f2b(oacc[t2][0][r]);
        op[16] = f2b(oacc[t2][1][r]);
      }
    }
}

extern "C" void kernel_launch(void* const* d_in, const int* in_sizes, int n_in,
                              void* d_out, int out_size, void* d_ws, size_t ws_size,
                              hipStream_t stream) {
  const float* x     = (const float*)d_in[0];
  const float* n1g   = (const float*)d_in[1];
  const float* n1b   = (const float*)d_in[2];
  const float* qkvw  = (const float*)d_in[3];
  const float* qkvb  = (const float*)d_in[4];
  const float* projw = (const float*)d_in[5];
  const float* projb = (const float*)d_in[6];
  const float* rpb   = (const float*)d_in[7];
  const float* n2g   = (const float*)d_in[8];
  const float* n2b   = (const float*)d_in[9];
  const float* fc1w  = (const float*)d_in[10];
  const float* fc1b  = (const float*)d_in[11];
  const float* fc2w  = (const float*)d_in[12];
  const float* fc2b  = (const float*)d_in[13];
  float* out = (float*)d_out;

  // ws layout (u16 units): weights 1.77M | region A 19.27M (xw -> obuf -> abuf) | region B 77.07M (qkv -> mid)
  u16* qkvwT  = (u16*)d_ws;                 // 442368
  u16* projwT = qkvwT + 442368;             // 147456
  u16* fc1wT  = projwT + 147456;            // 589824
  u16* fc2wT  = fc1wT + 589824;             // 589824  (ends 1769472)
  u16* wsA    = fc2wT + 589824;             // 19267584 (ends 21037056)
  u16* wsB    = wsA + 19267584;             // 77070336 (ends 98107392 = 196.2 MB)
  u16* xw   = wsA;        // LN1 out [50176][384]
  u16* obuf = wsA;        // attention out (xw dead after qkv GEMM)
  u16* abuf = wsA;        // LN2 out (obuf dead after proj)
  u16* qkvB = wsB;        // [50176][1152]
  u16* midB = wsB;        // [50176][1536] (qkv dead after attention)
  float* bmtb = (float*)qkvwT;  // 786KB bias+mask table aliases qkvwT (dead after qkv GEMM)

  // weights -> bf16 W^T
  wtrans<<<dim3(36, 12), dim3(32, 8), 0, stream>>>(qkvw, qkvwT, 384, 1152);
  wtrans<<<dim3(12, 12), dim3(32, 8), 0, stream>>>(projw, projwT, 384, 384);
  wtrans<<<dim3(48, 12), dim3(32, 8), 0, stream>>>(fc1w, fc1wT, 384, 1536);
  wtrans<<<dim3(12, 48), dim3(32, 8), 0, stream>>>(fc2w, fc2wT, 1536, 384);

  // 1. LN1 + shift + window -> xw
  ln_kernel<0><<<12544, 256, 0, stream>>>(x, n1g, n1b, xw);
  // 2. QKV GEMM -> qkvB
  gemm_big<0><<<dim3(392, 9), 256, 0, stream>>>(xw, qkvwT, qkvb, nullptr, qkvB, nullptr, 1152, 384);
  // 2b. bias+mask table (qkvwT now dead)
  bmt_kernel<<<dim3(4, 48), 256, 0, stream>>>(rpb, bmtb);
  // 3. windowed attention (MFMA, swapped QK^T) -> obuf
  attn_kernel<<<dim3(1024, 3), 256, 0, stream>>>(qkvB, bmtb, obuf);
  // 4. proj GEMM + reverse-shift scatter + shortcut -> d_out (x2, fp32)
  gemm_big<2><<<dim3(392, 3), 256, 0, stream>>>(obuf, projwT, projb, x, nullptr, out, 384, 384);
  // 5. LN2 -> abuf
  ln_kernel<1><<<12544, 256, 0, stream>>>(out, n2g, n2b, abuf);
  // 6. FC1 + GELU -> midB
  gemm_big<1><<<dim3(392, 12), 256, 0, stream>>>(abuf, fc1wT, fc1b, nullptr, midB, nullptr, 1536, 384);
  // 7. FC2 + residual RMW -> d_out
  gemm_big<3><<<dim3(392, 3), 256, 0, stream>>>(midB, fc2wT, fc2b, nullptr, nullptr, out, 384, 1536);
}

// Round 10
// 546.964 us; speedup vs baseline: 1.0690x; 1.0298x over previous
//
#include <hip/hip_runtime.h>

typedef unsigned short u16;
typedef unsigned int u32;
typedef __bf16 bf16x8 __attribute__((ext_vector_type(8)));
typedef float f32x4 __attribute__((ext_vector_type(4)));
typedef u32 u32x4 __attribute__((ext_vector_type(4)));
typedef u32 u32x2 __attribute__((ext_vector_type(2)));

union U8 { u32x4 u; u16 us[8]; bf16x8 bf; };

static __device__ __forceinline__ float b2f(u16 h) {
  union { u32 i; float f; } c; c.i = ((u32)h) << 16; return c.f;
}
static __device__ __forceinline__ u16 f2b(float f) {
  union { float f; u32 i; } c; c.f = f;
  u32 x = c.i;
  return (u16)((x + 0x7fffu + ((x >> 16) & 1u)) >> 16);
}
// pack 2 f32 -> 2 bf16 in one u32 (RTNE, identical to f2b pair)
static __device__ __forceinline__ u32 pk2(float a, float b) {
  u32 d;
  asm("v_cvt_pk_bf16_f32 %0, %1, %2" : "=v"(d) : "v"(a), "v"(b));
  return d;
}
// tanh-form GELU: v * sigmoid(2*0.79788456*(v + 0.044715 v^3)); |err vs erf-GELU| <= 3e-3
static __device__ __forceinline__ float gelu_f(float v) {
  float v2 = v * v;
  float ny2 = -2.0f * v * fmaf(0.0356774081f, v2, 0.7978845608f);   // -2y
  float sig = __builtin_amdgcn_rcpf(1.0f + __expf(ny2));
  return v * sig;
}

// async global->LDS DMA, 16B per lane, LDS dest = wave-uniform base + lane*16
#define G2LDS16(gp, lp)                                                                   \
  __builtin_amdgcn_global_load_lds((const __attribute__((address_space(1))) void*)(gp),   \
                                   (__attribute__((address_space(3))) void*)(lp), 16, 0, 0)

// ---------- weight transpose+convert: W[K][N] fp32 -> WT[N][K] bf16
__global__ __launch_bounds__(256) void wtrans(const float* __restrict__ W, u16* __restrict__ WT,
                                              int K, int N) {
  __shared__ float t[32][33];
  int n0 = blockIdx.x * 32, k0 = blockIdx.y * 32;
  int tx = threadIdx.x, ty = threadIdx.y;   // 32 x 8
#pragma unroll
  for (int r = 0; r < 4; ++r)
    t[ty + 8 * r][tx] = W[(long)(k0 + ty + 8 * r) * N + n0 + tx];
  __syncthreads();
#pragma unroll
  for (int r = 0; r < 4; ++r)
    WT[(long)(n0 + ty + 8 * r) * K + k0 + tx] = f2b(t[tx][ty + 8 * r]);
}

// ---------- LayerNorm: MODE 0 = shift+window gather (LN1), MODE 1 = direct rows (LN2)
// float2 loads (8B/lane coalesced) + packed u32 bf16 stores
template<int MODE>
__global__ __launch_bounds__(256) void ln_kernel(const float* __restrict__ src,
                                                 const float* __restrict__ g,
                                                 const float* __restrict__ b,
                                                 u16* __restrict__ dst) {
  int tok = blockIdx.x * 4 + (threadIdx.x >> 6);   // destination (windowed) token
  int lane = threadIdx.x & 63;
  long srow;
  if (MODE == 0) {
    int wg = tok / 49, i = tok % 49;
    int bimg = wg >> 4, wloc = wg & 15;
    int wh = wloc >> 2, ww = wloc & 3;
    int ih = i / 7, iw = i % 7;
    int hr = wh * 7 + ih + 3; if (hr >= 28) hr -= 28;  // roll(-3)
    int wr = ww * 7 + iw + 3; if (wr >= 28) wr -= 28;
    srow = (long)(bimg * 784 + hr * 28 + wr) * 384;
  } else {
    srow = (long)tok * 384;
  }
  const float* p = src + srow;
  float v[6];
#pragma unroll
  for (int t = 0; t < 3; ++t) {
    float2 z = *(const float2*)(p + (lane + 64 * t) * 2);
    v[2 * t] = z.x; v[2 * t + 1] = z.y;
  }
  float s = 0.f, ss = 0.f;
#pragma unroll
  for (int t = 0; t < 6; ++t) { s += v[t]; ss += v[t] * v[t]; }
  for (int m = 32; m; m >>= 1) { s += __shfl_xor(s, m); ss += __shfl_xor(ss, m); }
  float mean = s * (1.0f / 384.0f);
  float var  = ss * (1.0f / 384.0f) - mean * mean;
  float rs = rsqrtf(var + 1e-5f);
  u16* o = dst + (long)tok * 384;
#pragma unroll
  for (int t = 0; t < 3; ++t) {
    int ch = (lane + 64 * t) * 2;
    float2 gg = *(const float2*)(g + ch);
    float2 bb = *(const float2*)(b + ch);
    float r0 = (v[2 * t] - mean) * rs * gg.x + bb.x;
    float r1 = (v[2 * t + 1] - mean) * rs * gg.y + bb.y;
    *(u32*)&o[ch] = pk2(r0, r1);
  }
}

// ---------- big-tile GEMM: C[M][N] = A[M][K] @ BT[N][K]^T + bias
// BK=128 single-buffer: halves the number of stage->drain->barrier windows vs BK=64
// (K=384: 3 steps; K=1536: 12), which r6/r7/r9 A/Bs showed is the binding cost (all
// schedule variants at BK=64 land at ~110 µs). 64 KB LDS -> 2 blocks/CU so the
// remaining windows overlap across blocks. Swizzle generalized to 16-chunk rows:
// read slot (kk*4+quad)^(row&7), staged from source chunk ch^sr (odd calls ^4,
// valid since sr+4 == sr^4 for sr<4). Same bank math as the conflicts=0 BK=64 config.
// m204 bijective XCD remap + swapped-operand D^T epilogues retained.
template<int EPI>
__global__ __launch_bounds__(256, 2) void gemm_big(
    const u16* __restrict__ A, const u16* __restrict__ BT,
    const float* __restrict__ bias, const float* __restrict__ xres,
    u16* __restrict__ Cb, float* __restrict__ Cf, int N, int K) {
  __shared__ __align__(16) u16 As[128 * 128];   // 32 KB
  __shared__ __align__(16) u16 Bs[128 * 128];   // 32 KB
  const int tid = threadIdx.x;
  const int wave = tid >> 6, lane = tid & 63, quad = lane >> 4, col = lane & 15;

  const int NY = (EPI == 0) ? 9 : (EPI == 1) ? 12 : 3;     // N / 128
  // bijective XCD-chunked remap (m204)
  const int nwg = gridDim.x * gridDim.y;
  const int orig = blockIdx.x + blockIdx.y * gridDim.x;
  const int q8 = nwg >> 3, r8 = nwg & 7;
  const int xcd = orig & 7, idx = orig >> 3;
  const int sid = (xcd < r8 ? xcd * (q8 + 1) : r8 * (q8 + 1) + (xcd - r8) * q8) + idx;
  const int mi = sid / NY, ni = sid - mi * NY;             // N-inner within the chunk
  const long m0 = (long)mi * 128;
  const int n0 = ni * 128;

  const int rm = (wave & 1) * 64, cn = (wave >> 1) * 64;
  f32x4 acc[4][4];                          // acc[j][i]: n-tile j, m-tile i
#pragma unroll
  for (int j = 0; j < 4; ++j)
#pragma unroll
    for (int i = 0; i < 4; ++i) acc[j][i] = f32x4{0.f, 0.f, 0.f, 0.f};

  const int K128 = K >> 7;                  // 3 (K=384) or 12 (K=1536)
  // staging: wave w owns rows [w*32, w*32+32); 8 calls x (4 rows = 1KB) each for A,B.
  // call c covers rows w*32 + c*4 + sr (sr = lane>>4), chunk ch = lane&15.
  // LDS[row][slot] must hold A[row][slot ^ (row&7)]; (row&7) = (c*4+sr)&7 = 4*(c&1)+sr.
  const int sr4 = lane >> 4;                // sub-row within 4-row stripe
  const int ch = lane & 15;                 // 16B-chunk index within 256B row
  const u16* gAe = A  + (m0 + wave * 32 + sr4) * (long)K + ((ch ^ sr4) * 8);
  const u16* gBe = BT + ((long)(n0 + wave * 32 + sr4)) * K + ((ch ^ sr4) * 8);
  const u16* gAo = A  + (m0 + wave * 32 + sr4) * (long)K + ((ch ^ sr4 ^ 4) * 8);
  const u16* gBo = BT + ((long)(n0 + wave * 32 + sr4)) * K + ((ch ^ sr4 ^ 4) * 8);

  for (int kt = 0; kt < K128; ++kt) {
    if (kt) __syncthreads();                // all waves done reading previous tile
#pragma unroll
    for (int c = 0; c < 8; ++c) {
      const u16* pa = (c & 1) ? gAo : gAe;
      const u16* pb = (c & 1) ? gBo : gBe;
      G2LDS16(pa + (long)c * 4 * K + kt * 128, &As[(wave * 32 + c * 4) * 128] + lane * 8);
      G2LDS16(pb + (long)c * 4 * K + kt * 128, &Bs[(wave * 32 + c * 4) * 128] + lane * 8);
    }
    __syncthreads();                        // implicit vmcnt(0): tile ready
#pragma unroll
    for (int kk = 0; kk < 4; ++kk) {        // 4 x K=32 halves per BK=128 tile
      U8 af[4], bfr[4];
#pragma unroll
      for (int i = 0; i < 4; ++i) {
        int row = rm + i * 16 + col;
        int slot = (kk * 4 + quad) ^ (row & 7);
        af[i].u = *(const u32x4*)&As[row * 128 + slot * 8];
      }
#pragma unroll
      for (int j = 0; j < 4; ++j) {
        int row = cn + j * 16 + col;
        int slot = (kk * 4 + quad) ^ (row & 7);
        bfr[j].u = *(const u32x4*)&Bs[row * 128 + slot * 8];
      }
#pragma unroll
      for (int j = 0; j < 4; ++j)
#pragma unroll
        for (int i = 0; i < 4; ++i)
          acc[j][i] = __builtin_amdgcn_mfma_f32_16x16x32_bf16(bfr[j].bf, af[i].bf, acc[j][i], 0, 0, 0);
    }
  }

  // ---- epilogue (D^T layout: row = m0+rm+i*16+col, n = n0+cn+j*16+quad*4+r)
  if (EPI == 0 || EPI == 1) {
#pragma unroll
    for (int j = 0; j < 4; ++j) {
      int nb = n0 + cn + j * 16 + quad * 4;
      f32x4 bv = *(const f32x4*)&bias[nb];
#pragma unroll
      for (int i = 0; i < 4; ++i) {
        long row = m0 + rm + i * 16 + col;
        f32x4 v = acc[j][i] + bv;
        if (EPI == 1) {
#pragma unroll
          for (int r = 0; r < 4; ++r) v[r] = gelu_f(v[r]);
        }
        *(u32x2*)&Cb[row * N + nb] = u32x2{pk2(v[0], v[1]), pk2(v[2], v[3])};
      }
    }
  } else if (EPI == 2) {
#pragma unroll
    for (int i = 0; i < 4; ++i) {
      int row = (int)m0 + rm + i * 16 + col;
      int wg = row / 49, i49 = row - wg * 49;
      int bimg = wg >> 4, wloc = wg & 15;
      int wh = wloc >> 2, ww = wloc & 3;
      int ih = i49 / 7, iw = i49 - (i49 / 7) * 7;
      int ho = wh * 7 + ih + 3; if (ho >= 28) ho -= 28;   // roll(+3) back
      int wo = ww * 7 + iw + 3; if (wo >= 28) wo -= 28;
      long dstb = (long)(bimg * 784 + ho * 28 + wo) * 384;
#pragma unroll
      for (int j = 0; j < 4; ++j) {
        int nb = n0 + cn + j * 16 + quad * 4;
        f32x4 bv = *(const f32x4*)&bias[nb];
        f32x4 xr = *(const f32x4*)&xres[dstb + nb];
        f32x4 v = acc[j][i] + bv + xr;
        *(f32x4*)&Cf[dstb + nb] = v;
      }
    }
  } else {  // EPI == 3: fp32 RMW residual
#pragma unroll
    for (int i = 0; i < 4; ++i) {
      long rb = (long)((int)m0 + rm + i * 16 + col) * 384;
#pragma unroll
      for (int j = 0; j < 4; ++j) {
        int nb = n0 + cn + j * 16 + quad * 4;
        f32x4 bv = *(const f32x4*)&bias[nb];
        f32x4 old = *(const f32x4*)&Cf[rb + nb];
        f32x4 v = acc[j][i] + bv + old;
        *(f32x4*)&Cf[rb + nb] = v;
      }
    }
  }
}

// ---------- bias+mask table in SWAPPED C-fragment order:
// f32x4 at [((type*12+head)*16 + tj*4 + ti)*64 + quad*16 + c], elem r =
//   bias(i = ti*16+c, j = tj*16+quad*4+r); -1e30 padding for i>=49 or j>=49.
__global__ __launch_bounds__(256) void bmt_kernel(const float* __restrict__ rpb,
                                                  float* __restrict__ bmt) {
  int th = blockIdx.y;                       // type*12 + head
  int type = th / 12, head = th - type * 12;
  int e = blockIdx.x * 256 + threadIdx.x;    // [0,1024) per (type,head)
  int tj = e >> 8, ti = (e >> 6) & 3, quad = (e >> 4) & 3, c = e & 15;
  int i = ti * 16 + c;
  int ih = i / 7, iw = i - ih * 7;
  int regi = ((type & 2) ? ((ih < 4) ? 1 : 2) : 0) * 3 + ((type & 1) ? ((iw < 4) ? 1 : 2) : 0);
  f32x4 v;
#pragma unroll
  for (int r = 0; r < 4; ++r) {
    int j = tj * 16 + quad * 4 + r;
    float val = -1e30f;
    if (i < 49 && j < 49) {
      int jh = j / 7, jw = j - jh * 7;
      int idx = (ih - jh + 6) * 13 + (iw - jw + 6);
      val = rpb[idx * 12 + head];
      int regj = ((type & 2) ? ((jh < 4) ? 1 : 2) : 0) * 3 + ((type & 1) ? ((jw < 4) ? 1 : 2) : 0);
      if (regi != regj) val -= 100.0f;
    }
    v[r] = val;
  }
  ((f32x4*)bmt)[((long)th * 16 + tj * 4 + ti) * 64 + quad * 16 + c] = v;
}

// ---------- MFMA attention, swapped-QK^T design: wave = (window, head)
// S' = K·Q^T (A=K-frag, B=Q-frag), C-layout: lane holds S'[j=tj*16+quad*4+r][i=ti*16+c].
// Softmax over j: 16 in-lane + shfl_xor(16,32). P written row-major [i][j] to per-wave
// LDS with packed b64 (r's are consecutive j), read back as PV A-frags via plain
// contiguous ds_read_b128. V B-frags: 32 scalar reads from stride-130 Vs (conflict-free).
__global__ __launch_bounds__(256) void attn_kernel(const u16* __restrict__ qkv,
                                                   const float* __restrict__ bmt,
                                                   u16* __restrict__ obuf) {
  __shared__ __align__(16) u16 Ks[64 * 136];     // K row-major [j][d'], stride 136
  __shared__ __align__(16) u16 Vs[64 * 130];     // V row-major [j][d'], stride 130
  __shared__ __align__(16) u16 PL[4 * 64 * 72];  // per-wave P [i][j], stride 72
  const int w = blockIdx.x, h0 = blockIdx.y * 4;
  const int tid = threadIdx.x;
  const int hl = tid >> 6, lane = tid & 63, quad = lane >> 4, c = lane & 15;
  const int head = h0 + hl;
  const int wloc = w & 15;
  const int type = (((wloc >> 2) == 3) ? 2 : 0) + (((wloc & 3) == 3) ? 1 : 0);

  // stage K (u32x4 chunks, 128 u16 per row); zero rows j>=49 (mask padding must be finite)
#pragma unroll
  for (int it = 0; it < 4; ++it) {
    int cc = tid + it * 256;                 // 64 rows x 16 chunks
    int j = cc >> 4, ch = cc & 15;
    u32x4 val = {0u, 0u, 0u, 0u};
    if (j < 49)
      val = *(const u32x4*)(qkv + ((long)w * 49 + j) * 1152 + 384 + h0 * 32 + ch * 8);
    *(u32x4*)&Ks[j * 136 + ch * 8] = val;
  }
  // stage V: 64 rows x 64 u32-chunks = 128 u16 per row; zero rows j>=49
#pragma unroll
  for (int it = 0; it < 16; ++it) {
    int cc = tid + it * 256;
    int j = cc >> 6, c4 = cc & 63;
    u32 val = 0u;
    if (j < 49)
      val = *(const u32*)(qkv + ((long)w * 49 + j) * 1152 + 768 + h0 * 32 + c4 * 2);
    *(u32*)&Vs[j * 130 + c4 * 2] = val;
  }

  // Q B-frags from global: lane holds Q[i=ti*16+c][d=quad*8+e]  (= B[k=d][n=i])
  U8 qf[4];
#pragma unroll
  for (int ti = 0; ti < 4; ++ti)
    qf[ti].u = *(const u32x4*)(qkv + ((long)w * 49 + ti * 16 + c) * 1152 + head * 32 + quad * 8);
  __syncthreads();

  // K A-frags: lane holds K[j=tj*16+c][d=quad*8+e]; S' = K·Q^T (one MFMA per tile, K=32)
  U8 kf[4];
#pragma unroll
  for (int tj = 0; tj < 4; ++tj)
    kf[tj].u = *(const u32x4*)&Ks[(tj * 16 + c) * 136 + hl * 32 + quad * 8];
  f32x4 s[4][4];                             // [tj][ti]: S'[j][i]
#pragma unroll
  for (int tj = 0; tj < 4; ++tj)
#pragma unroll
    for (int ti = 0; ti < 4; ++ti)
      s[tj][ti] = __builtin_amdgcn_mfma_f32_16x16x32_bf16(kf[tj].bf, qf[ti].bf,
                                                          f32x4{0.f, 0.f, 0.f, 0.f}, 0, 0, 0);

  // scale + bias/mask (table in matching fragment order -> coalesced f32x4)
  const f32x4* btb = (const f32x4*)bmt + ((long)(type * 12 + head) * 16) * 64 + quad * 16 + c;
#pragma unroll
  for (int tj = 0; tj < 4; ++tj)
#pragma unroll
    for (int ti = 0; ti < 4; ++ti) {
      f32x4 bv = btb[(tj * 4 + ti) * 64];
#pragma unroll
      for (int r = 0; r < 4; ++r)
        s[tj][ti][r] = fmaf(s[tj][ti][r], 0.17677669529663689f, bv[r]);
    }

  // softmax over j for each i (= per ti, fixed c): 16 in-lane values + quads via xor 16,32
#pragma unroll
  for (int ti = 0; ti < 4; ++ti) {
    float m = -1e30f;
#pragma unroll
    for (int tj = 0; tj < 4; ++tj)
#pragma unroll
      for (int r = 0; r < 4; ++r) m = fmaxf(m, s[tj][ti][r]);
    m = fmaxf(m, __shfl_xor(m, 16));
    m = fmaxf(m, __shfl_xor(m, 32));
    float l = 0.f;
#pragma unroll
    for (int tj = 0; tj < 4; ++tj)
#pragma unroll
      for (int r = 0; r < 4; ++r) {
        float p = __expf(s[tj][ti][r] - m);
        s[tj][ti][r] = p;
        l += p;
      }
    l += __shfl_xor(l, 16);
    l += __shfl_xor(l, 32);
    float inv = 1.0f / l;
#pragma unroll
    for (int tj = 0; tj < 4; ++tj)
#pragma unroll
      for (int r = 0; r < 4; ++r) s[tj][ti][r] *= inv;
  }

  // write P row-major [i][j] (bf16): r=0..3 are consecutive j -> one b64 per (ti,tj)
#pragma unroll
  for (int ti = 0; ti < 4; ++ti)
#pragma unroll
    for (int tj = 0; tj < 4; ++tj) {
      u32 lo = pk2(s[tj][ti][0], s[tj][ti][1]);
      u32 hi = pk2(s[tj][ti][2], s[tj][ti][3]);
      *(u32x2*)&PL[hl * 4608 + (ti * 16 + c) * 72 + tj * 16 + quad * 4] = u32x2{lo, hi};
    }

  // PV: O[i][d] = sum_j P[i][j] V[j][d]
  f32x4 oacc[4][2];
#pragma unroll
  for (int t2 = 0; t2 < 4; ++t2) {
    oacc[t2][0] = f32x4{0.f, 0.f, 0.f, 0.f};
    oacc[t2][1] = f32x4{0.f, 0.f, 0.f, 0.f};
  }
#pragma unroll
  for (int kk = 0; kk < 2; ++kk) {
    U8 pa[4];                                // A-frag: P[i=t2*16+c][j=kk*32+quad*8+e]
#pragma unroll
    for (int t2 = 0; t2 < 4; ++t2)
      pa[t2].u = *(const u32x4*)&PL[hl * 4608 + (t2 * 16 + c) * 72 + kk * 32 + quad * 8];
    U8 vf[2];                                // B-frag: V[j=kk*32+quad*8+e][d=td*16+c]
#pragma unroll
    for (int td = 0; td < 2; ++td)
#pragma unroll
      for (int e = 0; e < 8; ++e)
        vf[td].us[e] = Vs[(kk * 32 + quad * 8 + e) * 130 + hl * 32 + td * 16 + c];
#pragma unroll
    for (int t2 = 0; t2 < 4; ++t2)
#pragma unroll
      for (int td = 0; td < 2; ++td)
        oacc[t2][td] = __builtin_amdgcn_mfma_f32_16x16x32_bf16(pa[t2].bf, vf[td].bf, oacc[t2][td], 0, 0, 0);
  }

  // store O rows i<49; lane holds O[i=t2*16+quad*4+r][d=td*16+c]
#pragma unroll
  for (int t2 = 0; t2 < 4; ++t2)
#pragma unroll
    for (int r = 0; r < 4; ++r) {
      int i = t2 * 16 + quad * 4 + r;
      if (i < 49) {
        u16* op = obuf + ((long)w * 49 + i) * 384 + head * 32 + c;
        op[0]  = f2b(oacc[t2][0][r]);
        op[16] = f2b(oacc[t2][1][r]);
      }
    }
}

extern "C" void kernel_launch(void* const* d_in, const int* in_sizes, int n_in,
                              void* d_out, int out_size, void* d_ws, size_t ws_size,
                              hipStream_t stream) {
  const float* x     = (const float*)d_in[0];
  const float* n1g   = (const float*)d_in[1];
  const float* n1b   = (const float*)d_in[2];
  const float* qkvw  = (const float*)d_in[3];
  const float* qkvb  = (const float*)d_in[4];
  const float* projw = (const float*)d_in[5];
  const float* projb = (const float*)d_in[6];
  const float* rpb   = (const float*)d_in[7];
  const float* n2g   = (const float*)d_in[8];
  const float* n2b   = (const float*)d_in[9];
  const float* fc1w  = (const float*)d_in[10];
  const float* fc1b  = (const float*)d_in[11];
  const float* fc2w  = (const float*)d_in[12];
  const float* fc2b  = (const float*)d_in[13];
  float* out = (float*)d_out;

  // ws layout (u16 units): weights 1.77M | region A 19.27M (xw -> obuf -> abuf) | region B 77.07M (qkv -> mid)
  u16* qkvwT  = (u16*)d_ws;                 // 442368
  u16* projwT = qkvwT + 442368;             // 147456
  u16* fc1wT  = projwT + 147456;            // 589824
  u16* fc2wT  = fc1wT + 589824;             // 589824  (ends 1769472)
  u16* wsA    = fc2wT + 589824;             // 19267584 (ends 21037056)
  u16* wsB    = wsA + 19267584;             // 77070336 (ends 98107392 = 196.2 MB)
  u16* xw   = wsA;        // LN1 out [50176][384]
  u16* obuf = wsA;        // attention out (xw dead after qkv GEMM)
  u16* abuf = wsA;        // LN2 out (obuf dead after proj)
  u16* qkvB = wsB;        // [50176][1152]
  u16* midB = wsB;        // [50176][1536] (qkv dead after attention)
  float* bmtb = (float*)qkvwT;  // 786KB bias+mask table aliases qkvwT (dead after qkv GEMM)

  // weights -> bf16 W^T
  wtrans<<<dim3(36, 12), dim3(32, 8), 0, stream>>>(qkvw, qkvwT, 384, 1152);
  wtrans<<<dim3(12, 12), dim3(32, 8), 0, stream>>>(projw, projwT, 384, 384);
  wtrans<<<dim3(48, 12), dim3(32, 8), 0, stream>>>(fc1w, fc1wT, 384, 1536);
  wtrans<<<dim3(12, 48), dim3(32, 8), 0, stream>>>(fc2w, fc2wT, 1536, 384);

  // 1. LN1 + shift + window -> xw
  ln_kernel<0><<<12544, 256, 0, stream>>>(x, n1g, n1b, xw);
  // 2. QKV GEMM -> qkvB
  gemm_big<0><<<dim3(392, 9), 256, 0, stream>>>(xw, qkvwT, qkvb, nullptr, qkvB, nullptr, 1152, 384);
  // 2b. bias+mask table (qkvwT now dead)
  bmt_kernel<<<dim3(4, 48), 256, 0, stream>>>(rpb, bmtb);
  // 3. windowed attention (MFMA, swapped QK^T) -> obuf
  attn_kernel<<<dim3(1024, 3), 256, 0, stream>>>(qkvB, bmtb, obuf);
  // 4. proj GEMM + reverse-shift scatter + shortcut -> d_out (x2, fp32)
  gemm_big<2><<<dim3(392, 3), 256, 0, stream>>>(obuf, projwT, projb, x, nullptr, out, 384, 384);
  // 5. LN2 -> abuf
  ln_kernel<1><<<12544, 256, 0, stream>>>(out, n2g, n2b, abuf);
  // 6. FC1 + GELU -> midB
  gemm_big<1><<<dim3(392, 12), 256, 0, stream>>>(abuf, fc1wT, fc1b, nullptr, midB, nullptr, 1536, 384);
  // 7. FC2 + residual RMW -> d_out
  gemm_big<3><<<dim3(392, 3), 256, 0, stream>>>(midB, fc2wT, fc2b, nullptr, nullptr, out, 384, 1536);
}